// Round 18
// baseline (122.765 us; speedup 1.0000x reference)
//
#include <hip/hip_runtime.h>

// ---------------------------------------------------------------------------
// GCN 3-layer forward on a static graph.
// R2-R6: tiled SGEMM, parallel scan, int2 CSR, LDS histograms/rank-scatter.
// R7-R9: f32 SGEMM structurally capped ~45us (LDS pipe vs 4 SIMDs).
// R10: bf16 split-precision MFMA GEMM: 168->141.5us.
// R11: bf16 HT gather operand: ->124us (absmax 3e-5 -> 6.1e-5).
// R12: preprocessing occupancy (NB=256, u8 gpre, 2-stage norm): ->111.5us.
// R13: gemm reg-prefetch; ACT1 bf16; norm folded into csr_w: ->107.7us.
// R14: calibrated precision cuts: ->105.4us, absmax pinned 6.1e-5.
// R15/R16: cooperative mega-fusion DEAD (grid.sync ~35us each on 8 XCDs).
// R17: norm_reduce fusion NEGATIVE (+2.7us) -- reverted to R14 norm pair.
// R18: fuse aggregate1+gemm2 into one kernel: gemm2 row r depends only on
//     ACT1 row r, which the same block just aggregated -> Phase A gathers
//     64 nodes into an LDS bf16 tile, Phase B runs the 128->64 MFMA GEMM
//     from LDS. Deletes ACT1 global round-trip (16 MB) + one launch/gap.
// ---------------------------------------------------------------------------

#define NB 256     // edge groups == hist/scatter blocks
#define NW4 8192   // N/4 packed words (N = 32768)
#define RSEG 8     // r-segments for the 2-stage partials reduction

typedef unsigned int uint32;
typedef unsigned char uchar_t;
typedef unsigned short ushort_t;
typedef __attribute__((ext_vector_type(8))) short bf16x8;
typedef __attribute__((ext_vector_type(4))) float f32x4;

__device__ inline ushort_t f2bf(float f) {
  uint32 u = __float_as_uint(f);
  u += 0x7fffu + ((u >> 16) & 1u);
  return (ushort_t)(u >> 16);
}
__device__ inline float bf2f(ushort_t h) { return __uint_as_float(((uint32)h) << 16); }

// tanh = (e^{2x}-1)/(e^{2x}+1)
__device__ inline float fast_tanh(float x) {
  float xc = fminf(fmaxf(x, -30.f), 30.f);
  float t = __expf(2.0f * xc);
  return (t - 1.0f) * __builtin_amdgcn_rcpf(t + 1.0f);
}

// --- hist (blocks < NB) + W pre-split (blocks >= NB) ------------------------
__global__ __launch_bounds__(1024) void hist_wsplit_kernel(
    const int* __restrict__ src, const int* __restrict__ dst, uint32* __restrict__ part,
    const float* __restrict__ W1, const float* __restrict__ W2,
    ushort_t* __restrict__ WhT1, ushort_t* __restrict__ WlT1,
    ushort_t* __restrict__ WhT2, int e, int epb) {
  const int t = threadIdx.x;
  if (blockIdx.x >= NB) {
    int i = (blockIdx.x - NB) * 1024 + t;
    if (i < 256 * 128) {
      int k = i / 128, c = i % 128;
      float f = W1[i];
      ushort_t h = f2bf(f);
      WhT1[(size_t)c * 256 + k] = h;
      WlT1[(size_t)c * 256 + k] = f2bf(f - bf2f(h));
    } else if (i < 256 * 128 + 128 * 64) {
      int j = i - 256 * 128;
      int k = j / 64, c = j % 64;
      WhT2[(size_t)c * 128 + k] = f2bf(W2[j]);
    }
    return;
  }
  __shared__ uint32 hs[NW4];
  __shared__ uint32 hd[NW4];
  for (int w = t; w < NW4; w += 1024) {
    hs[w] = 0;
    hd[w] = 0;
  }
  __syncthreads();
  const int base = blockIdx.x * epb;
  for (int k = t; k < epb; k += 1024) {
    int i = base + k;
    if (i < e) {
      int s = src[i], d = dst[i];
      atomicAdd(&hs[s >> 2], 1u << ((s & 3) * 8));
      atomicAdd(&hd[d >> 2], 1u << ((d & 3) * 8));
    }
  }
  __syncthreads();
  uint32* ps = part + (size_t)blockIdx.x * NW4;
  uint32* pd = part + (size_t)(NB + blockIdx.x) * NW4;
  for (int w = t; w < NW4; w += 1024) {
    ps[w] = hs[w];
    pd[w] = hd[w];
  }
}

// --- stage A: sum NB/RSEG r-values per word per segment ---------------------
__global__ __launch_bounds__(256) void norm_partial(const uint32* __restrict__ part,
                                                    uint32* __restrict__ psum, int n4) {
  const int w = blockIdx.x * 256 + threadIdx.x;
  const int seg = blockIdx.y;
  const int a = blockIdx.z;
  const uint32* p = part + (size_t)a * NB * n4 + (size_t)seg * (NB / RSEG) * n4 + w;
  uint32 s = 0;
#pragma unroll
  for (int r = 0; r < NB / RSEG; ++r) s += p[(size_t)r * n4];
  psum[(size_t)a * RSEG * n4 + (size_t)seg * n4 + w] = s;
}

// --- stage B: fold segments -> norms/in_deg + chunk sums --------------------
__global__ __launch_bounds__(256) void norm_final(const uint32* __restrict__ psum,
                                                  float* __restrict__ norm_src,
                                                  float* __restrict__ norm_dst,
                                                  int* __restrict__ in_deg,
                                                  int* __restrict__ block_sums, int n4) {
  const int w = blockIdx.x * 256 + threadIdx.x;
  if (w >= n4) return;
  uint32 ss = 0, sd = 0;
#pragma unroll
  for (int seg = 0; seg < RSEG; ++seg) {
    ss += psum[(size_t)seg * n4 + w];
    sd += psum[(size_t)(RSEG + seg) * n4 + w];
  }
  int idsum = 0;
#pragma unroll
  for (int j = 0; j < 4; ++j) {
    int v = w * 4 + j;
    int od = (ss >> (j * 8)) & 0xff;
    int id = (sd >> (j * 8)) & 0xff;
    norm_src[v] = 1.0f / sqrtf((float)max(od, 1));
    norm_dst[v] = 1.0f / sqrtf((float)max(id, 1));
    in_deg[v] = id;
    idsum += id;
  }
#pragma unroll
  for (int off = 32; off > 0; off >>= 1) idsum += __shfl_down(idsum, off, 64);
  if ((threadIdx.x & 63) == 0) block_sums[w >> 6] = idsum;
}

// --- chunk scan (block offset inlined) -> row_ptr + u8 group offsets --------
__global__ __launch_bounds__(256) void scan_write_goffs(const int* __restrict__ in_deg,
                                                        const int* __restrict__ block_sums,
                                                        const uint32* __restrict__ part_dst,
                                                        int* __restrict__ row_ptr,
                                                        uchar_t* __restrict__ gpre, int n) {
  __shared__ int sh[256];
  __shared__ int s_boff;
  const int t = threadIdx.x;
  const int gid = blockIdx.x * 256 + t;
  {
    int v = (t < blockIdx.x && t < 128) ? block_sums[t] : 0;
#pragma unroll
    for (int off = 32; off > 0; off >>= 1) v += __shfl_down(v, off, 64);
    if ((t & 63) == 0) sh[t >> 6] = v;
    __syncthreads();
    if (t == 0) s_boff = sh[0] + sh[1];
    __syncthreads();
  }
  int d = (gid < n) ? in_deg[gid] : 0;
  sh[t] = d;
  __syncthreads();
  for (int off = 1; off < 256; off <<= 1) {
    int v = sh[t];
    int add = (t >= off) ? sh[t - off] : 0;
    __syncthreads();
    sh[t] = v + add;
    __syncthreads();
  }
  if (gid >= n) return;
  int excl = s_boff + sh[t] - d;
  row_ptr[gid] = excl;
  if (gid == n - 1) row_ptr[n] = excl + d;
  const int w = gid >> 2;
  const int shft = (gid & 3) * 8;
  const int n4 = n >> 2;
  int cum = 0;
#pragma unroll 8
  for (int r = 0; r < NB; ++r) {
    gpre[(size_t)r * n + gid] = (uchar_t)cum;
    cum += (part_dst[(size_t)r * n4 + w] >> shft) & 0xff;
  }
}

// --- scatter: LDS rank + row_ptr + gpre; csr weight = ew * norm_src[src] ----
__global__ __launch_bounds__(1024) void scatter_kernel(const int* __restrict__ src,
                                                       const int* __restrict__ dst,
                                                       const float* __restrict__ ew,
                                                       const float* __restrict__ norm_src,
                                                       const int* __restrict__ row_ptr,
                                                       const uchar_t* __restrict__ gpre,
                                                       int2* __restrict__ csr,
                                                       int n, int e, int epb) {
  __shared__ uint32 rk[NW4];
  const int t = threadIdx.x;
  for (int w = t; w < NW4; w += 1024) rk[w] = 0;
  __syncthreads();
  const int base = blockIdx.x * epb;
  const uchar_t* gp = gpre + (size_t)blockIdx.x * n;
  for (int k = t; k < epb; k += 1024) {
    int i = base + k;
    if (i < e) {
      int s = src[i];
      int d = dst[i];
      uint32 sh = (d & 3) * 8;
      uint32 old = atomicAdd(&rk[d >> 2], 1u << sh);
      int rank = (old >> sh) & 0xff;
      int pos = row_ptr[d] + (int)gp[d] + rank;
      csr[pos] = make_int2(s, __float_as_int(ew[i] * norm_src[s]));
    }
  }
}

// ---------------------------------------------------------------------------
// MFMA GEMM, f32 input rounded to bf16-high: ht = bf16(x @ W), 2 MFMAs.
// ---------------------------------------------------------------------------
template <int K, int OUT>
__global__ __launch_bounds__(256) void gemm_mfma(const float* __restrict__ x,
                                                 const ushort_t* __restrict__ WhT,
                                                 const ushort_t* __restrict__ WlT,
                                                 ushort_t* __restrict__ ht, int n) {
  constexpr int BK = 64, KP = BK + 8;
  constexpr int NCT = OUT / 32;
  constexpr int NWLD = OUT * 16 / 256;
  __shared__ ushort_t Xh[64][KP];
  __shared__ ushort_t Wh[OUT][KP], Wl[OUT][KP];

  const int tid = threadIdx.x;
  const int wv = tid >> 6;
  const int lane = tid & 63;
  const int wr = wv >> 1;
  const int wc = wv & 1;
  const int row0 = blockIdx.x * 64;
  const int fr = lane & 15;
  const int fg = lane >> 4;

  f32x4 acc[2][NCT];
#pragma unroll
  for (int i = 0; i < 2; ++i)
#pragma unroll
    for (int j = 0; j < NCT; ++j) acc[i][j] = (f32x4){0.f, 0.f, 0.f, 0.f};

  float4 xr[4];
  ushort4 wrh[NWLD], wrl[NWLD];

#define LOADX(kg)                                                                       \
  {                                                                                     \
    _Pragma("unroll") for (int p_ = 0; p_ < 4; ++p_) {                                  \
      int idx_ = p_ * 256 + tid;                                                        \
      xr[p_] = *reinterpret_cast<const float4*>(                                        \
          x + (size_t)(row0 + (idx_ >> 4)) * K + (kg) + (idx_ & 15) * 4);               \
    }                                                                                   \
  }
#define LOADW(kg)                                                                       \
  {                                                                                     \
    _Pragma("unroll") for (int p_ = 0; p_ < NWLD; ++p_) {                               \
      int idx_ = p_ * 256 + tid;                                                        \
      int c_ = idx_ >> 4, k4_ = idx_ & 15;                                              \
      wrh[p_] = *reinterpret_cast<const ushort4*>(WhT + (size_t)c_ * K + (kg) + k4_ * 4);\
      wrl[p_] = *reinterpret_cast<const ushort4*>(WlT + (size_t)c_ * K + (kg) + k4_ * 4);\
    }                                                                                   \
  }

  LOADX(0);
  LOADW(0);

#pragma unroll 1
  for (int k0 = 0; k0 < K; k0 += BK) {
    __syncthreads();
#pragma unroll
    for (int p = 0; p < 4; ++p) {
      int idx = p * 256 + tid;
      int r = idx >> 4, c4 = idx & 15;
      float4 v = xr[p];
      ushort4 h;
      h.x = f2bf(v.x);
      h.y = f2bf(v.y);
      h.z = f2bf(v.z);
      h.w = f2bf(v.w);
      *reinterpret_cast<ushort4*>(&Xh[r][c4 * 4]) = h;
    }
#pragma unroll
    for (int p = 0; p < NWLD; ++p) {
      int idx = p * 256 + tid;
      int c = idx >> 4, k4 = idx & 15;
      *reinterpret_cast<ushort4*>(&Wh[c][k4 * 4]) = wrh[p];
      *reinterpret_cast<ushort4*>(&Wl[c][k4 * 4]) = wrl[p];
    }
    if (k0 + BK < K) {
      LOADX(k0 + BK);
      LOADW(k0 + BK);
    }
    __syncthreads();

#pragma unroll
    for (int s = 0; s < 2; ++s) {
      const int kk = s * 32 + fg * 8;
      bf16x8 ah[2];
#pragma unroll
      for (int i = 0; i < 2; ++i)
        ah[i] = *reinterpret_cast<const bf16x8*>(&Xh[wr * 32 + i * 16 + fr][kk]);
#pragma unroll
      for (int j = 0; j < NCT; ++j) {
        int c = wc * (OUT / 2) + j * 16 + fr;
        bf16x8 bh = *reinterpret_cast<const bf16x8*>(&Wh[c][kk]);
        bf16x8 bl = *reinterpret_cast<const bf16x8*>(&Wl[c][kk]);
#pragma unroll
        for (int i = 0; i < 2; ++i) {
          acc[i][j] = __builtin_amdgcn_mfma_f32_16x16x32_bf16(ah[i], bh, acc[i][j], 0, 0, 0);
          acc[i][j] = __builtin_amdgcn_mfma_f32_16x16x32_bf16(ah[i], bl, acc[i][j], 0, 0, 0);
        }
      }
    }
  }
#undef LOADX
#undef LOADW

#pragma unroll
  for (int i = 0; i < 2; ++i) {
#pragma unroll
    for (int q = 0; q < 4; ++q) {
      int row = row0 + wr * 32 + i * 16 + fg * 4 + q;
#pragma unroll
      for (int j = 0; j < NCT; ++j) {
        int col = wc * (OUT / 2) + j * 16 + fr;
        ht[(size_t)row * OUT + col] = f2bf(acc[i][j][q]);
      }
    }
  }
}

// bf16 gather from 128-wide ht1
#define GATHB1(e, acc)                                                               \
  {                                                                                  \
    float w_ = __int_as_float(e.y);                                                  \
    ushort4 h_ = *reinterpret_cast<const ushort4*>(ht + (size_t)e.x * 128 + cg * 4); \
    acc.x += w_ * bf2f(h_.x);                                                        \
    acc.y += w_ * bf2f(h_.y);                                                        \
    acc.z += w_ * bf2f(h_.z);                                                        \
    acc.w += w_ * bf2f(h_.w);                                                        \
  }

// ---------------------------------------------------------------------------
// Fused aggregate1 (tanh, bf16) + gemm2 (128->64, W bf16-high, MFMA).
// Block owns 64 nodes. Phase A: 8 passes x 8 nodes, gather from ht1, write
// post-tanh bf16 rows to LDS ACT tile. Phase B: MFMA GEMM from LDS -> ht2.
// ---------------------------------------------------------------------------
__global__ __launch_bounds__(256) void agg1_gemm2(const ushort_t* __restrict__ ht,
                                                  const int* __restrict__ row_ptr,
                                                  const int2* __restrict__ csr,
                                                  const float* __restrict__ norm_dst,
                                                  const float* __restrict__ b1,
                                                  const ushort_t* __restrict__ WhT2,
                                                  ushort_t* __restrict__ ht2, int n) {
  constexpr int K = 128, OUT = 64, KP = K + 8; // 136 (272B rows, 16B-aligned)
  __shared__ ushort_t ACT[64][KP];
  __shared__ ushort_t WL[OUT][KP];

  const int tid = threadIdx.x;
  const int v0 = blockIdx.x * 64;

  // stage WhT2 (64 x 128 bf16): 2048 ushort4 / 256 threads = 8 each
#pragma unroll
  for (int p = 0; p < 8; ++p) {
    int idx = p * 256 + tid;
    int c = idx >> 5, k4 = idx & 31;
    *reinterpret_cast<ushort4*>(&WL[c][k4 * 4]) =
        *reinterpret_cast<const ushort4*>(WhT2 + (size_t)c * K + k4 * 4);
  }

  // Phase A: aggregate layer-1 for 64 nodes (8 per pass)
  const int cg = tid & 31;  // col group (4 cols) of the 128-wide row
  const int vsub = tid >> 5;
#pragma unroll 1
  for (int p = 0; p < 8; ++p) {
    const int lv = p * 8 + vsub;
    const int v = v0 + lv;
    const int s0 = row_ptr[v];
    const int s1 = row_ptr[v + 1];
    float4 a0 = {0, 0, 0, 0}, a1 = {0, 0, 0, 0}, a2 = {0, 0, 0, 0}, a3 = {0, 0, 0, 0};
    int i = s0;
    for (; i + 4 <= s1; i += 4) {
      int2 e0 = csr[i], e1 = csr[i + 1], e2 = csr[i + 2], e3 = csr[i + 3];
      GATHB1(e0, a0);
      GATHB1(e1, a1);
      GATHB1(e2, a2);
      GATHB1(e3, a3);
    }
    for (; i < s1; ++i) {
      int2 e = csr[i];
      GATHB1(e, a0);
    }
    float nd = norm_dst[v];
    float4 b4 = *reinterpret_cast<const float4*>(b1 + cg * 4);
    ushort4 r;
    r.x = f2bf(fast_tanh((a0.x + a1.x + a2.x + a3.x) * nd + b4.x));
    r.y = f2bf(fast_tanh((a0.y + a1.y + a2.y + a3.y) * nd + b4.y));
    r.z = f2bf(fast_tanh((a0.z + a1.z + a2.z + a3.z) * nd + b4.z));
    r.w = f2bf(fast_tanh((a0.w + a1.w + a2.w + a3.w) * nd + b4.w));
    *reinterpret_cast<ushort4*>(&ACT[lv][cg * 4]) = r;
  }
  __syncthreads();

  // Phase B: gemm2 from LDS (K=128, 4 k-slices, 1 MFMA each)
  const int wv = tid >> 6;
  const int lane = tid & 63;
  const int wr = wv >> 1;
  const int wc = wv & 1;
  const int fr = lane & 15;
  const int fg = lane >> 4;

  f32x4 acc[2][2];
#pragma unroll
  for (int i = 0; i < 2; ++i)
#pragma unroll
    for (int j = 0; j < 2; ++j) acc[i][j] = (f32x4){0.f, 0.f, 0.f, 0.f};

#pragma unroll
  for (int s = 0; s < 4; ++s) {
    const int kk = s * 32 + fg * 8;
    bf16x8 ah[2];
#pragma unroll
    for (int i = 0; i < 2; ++i)
      ah[i] = *reinterpret_cast<const bf16x8*>(&ACT[wr * 32 + i * 16 + fr][kk]);
#pragma unroll
    for (int j = 0; j < 2; ++j) {
      int c = wc * 32 + j * 16 + fr;
      bf16x8 bh = *reinterpret_cast<const bf16x8*>(&WL[c][kk]);
#pragma unroll
      for (int i = 0; i < 2; ++i)
        acc[i][j] = __builtin_amdgcn_mfma_f32_16x16x32_bf16(ah[i], bh, acc[i][j], 0, 0, 0);
    }
  }

#pragma unroll
  for (int i = 0; i < 2; ++i) {
#pragma unroll
    for (int q = 0; q < 4; ++q) {
      int row = v0 + wr * 32 + i * 16 + fg * 4 + q;
#pragma unroll
      for (int j = 0; j < 2; ++j) {
        int col = wc * 32 + j * 16 + fr;
        ht2[(size_t)row * OUT + col] = f2bf(acc[i][j][q]);
      }
    }
  }
}

// bf16 gather from 64-wide ht2
#define GATHB2(e, acc)                                                              \
  {                                                                                 \
    float w_ = __int_as_float(e.y);                                                 \
    ushort4 h_ = *reinterpret_cast<const ushort4*>(ht + (size_t)e.x * 64 + cg * 4); \
    acc.x += w_ * bf2f(h_.x);                                                       \
    acc.y += w_ * bf2f(h_.y);                                                       \
    acc.z += w_ * bf2f(h_.z);                                                       \
    acc.w += w_ * bf2f(h_.w);                                                       \
  }

// Layer-2 aggregate fused with layer-3 transform (norm folded into csr_w).
__global__ void aggregate2_fuse3(const ushort_t* __restrict__ ht, const int* __restrict__ row_ptr,
                                 const int2* __restrict__ csr, const float* __restrict__ norm_dst,
                                 const float* __restrict__ bias, const float* __restrict__ W3,
                                 float* __restrict__ ht3, int n) {
  constexpr int LPN = 16;
  constexpr int NPB = 256 / LPN;
  const int tid = threadIdx.x;
  const int cg = tid % LPN;
  const int v = blockIdx.x * NPB + tid / LPN;
  if (v >= n) return;

  const int s0 = row_ptr[v];
  const int s1 = row_ptr[v + 1];
  float4 a0 = {0, 0, 0, 0}, a1 = {0, 0, 0, 0}, a2 = {0, 0, 0, 0}, a3 = {0, 0, 0, 0};
  int i = s0;
  for (; i + 4 <= s1; i += 4) {
    int2 e0 = csr[i], e1 = csr[i + 1], e2 = csr[i + 2], e3 = csr[i + 3];
    GATHB2(e0, a0);
    GATHB2(e1, a1);
    GATHB2(e2, a2);
    GATHB2(e3, a3);
  }
  for (; i < s1; ++i) {
    int2 e = csr[i];
    GATHB2(e, a0);
  }
  float nd = norm_dst[v];
  float4 b4 = *reinterpret_cast<const float4*>(bias + cg * 4);
  float ox = fast_tanh((a0.x + a1.x + a2.x + a3.x) * nd + b4.x);
  float oy = fast_tanh((a0.y + a1.y + a2.y + a3.y) * nd + b4.y);
  float oz = fast_tanh((a0.z + a1.z + a2.z + a3.z) * nd + b4.z);
  float ow = fast_tanh((a0.w + a1.w + a2.w + a3.w) * nd + b4.w);
  float4 w3 = *reinterpret_cast<const float4*>(W3 + cg * 4);
  float p = ox * w3.x + oy * w3.y + oz * w3.z + ow * w3.w;
#pragma unroll
  for (int m = 1; m < 16; m <<= 1) p += __shfl_xor(p, m, 64);
  if (cg == 0) ht3[v] = p;
}

__global__ void aggregate3_kernel(const float* __restrict__ ht3, const int* __restrict__ row_ptr,
                                  const int2* __restrict__ csr, const float* __restrict__ norm_dst,
                                  const float* __restrict__ b3, float* __restrict__ out, int n) {
  int v = blockIdx.x * blockDim.x + threadIdx.x;
  if (v >= n) return;
  const int s0 = row_ptr[v];
  const int s1 = row_ptr[v + 1];
  float p0 = 0.f, p1 = 0.f, p2 = 0.f, p3 = 0.f;
  int i = s0;
  for (; i + 4 <= s1; i += 4) {
    int2 e0 = csr[i], e1 = csr[i + 1], e2 = csr[i + 2], e3 = csr[i + 3];
    p0 += __int_as_float(e0.y) * ht3[e0.x];
    p1 += __int_as_float(e1.y) * ht3[e1.x];
    p2 += __int_as_float(e2.y) * ht3[e2.x];
    p3 += __int_as_float(e3.y) * ht3[e3.x];
  }
  for (; i < s1; ++i) {
    int2 e = csr[i];
    p0 += __int_as_float(e.y) * ht3[e.x];
  }
  out[v] = (p0 + p1 + p2 + p3) * norm_dst[v] + b3[0];
}

extern "C" void kernel_launch(void* const* d_in, const int* in_sizes, int n_in,
                              void* d_out, int out_size, void* d_ws, size_t ws_size,
                              hipStream_t stream) {
  const float* b_z = (const float*)d_in[0];
  const int* src = (const int*)d_in[1];
  const int* dst = (const int*)d_in[2];
  const float* ew = (const float*)d_in[3];
  const float* W1 = (const float*)d_in[4];
  const float* b1 = (const float*)d_in[5];
  const float* W2 = (const float*)d_in[6];
  const float* b2 = (const float*)d_in[7];
  const float* W3 = (const float*)d_in[8];
  const float* b3 = (const float*)d_in[9];

  const int N = in_sizes[0] / 256; // 32768
  const int E = in_sizes[1];       // 524288
  const int N4 = N / 4;            // 8192
  const int epb = (E + NB - 1) / NB; // 2048

  char* ws = (char*)d_ws;
  size_t off = 0;
  auto alloc = [&](size_t bytes) -> void* {
    void* p = ws + off;
    off += (bytes + 255) & ~(size_t)255;
    return p;
  };

  uint32* part = (uint32*)alloc((size_t)2 * NB * N4 * 4);   // 16 MB
  uint32* psum = (uint32*)alloc((size_t)2 * RSEG * N4 * 4); // 512 KB
  uchar_t* gpre = (uchar_t*)alloc((size_t)NB * N);          // 8 MB
  float* norm_src = (float*)alloc((size_t)N * 4);
  float* norm_dst = (float*)alloc((size_t)N * 4);
  int* in_deg = (int*)alloc((size_t)N * 4);
  int* row_ptr = (int*)alloc((size_t)(N + 1) * 4);
  int* block_sums = (int*)alloc(256 * 4);
  int2* csr = (int2*)alloc((size_t)E * 8);
  ushort_t* HT1 = (ushort_t*)alloc((size_t)N * 128 * 2); // bf16 layer1 transform
  ushort_t* HT2 = (ushort_t*)alloc((size_t)N * 64 * 2);  // bf16 layer2 transform
  float* HT3 = (float*)alloc((size_t)N * 4);
  ushort_t* WhT1 = (ushort_t*)alloc((size_t)256 * 128 * 2);
  ushort_t* WlT1 = (ushort_t*)alloc((size_t)256 * 128 * 2);
  ushort_t* WhT2 = (ushort_t*)alloc((size_t)128 * 64 * 2);

  const uint32* part_dst = part + (size_t)NB * N4;
  const int nBlocks = (N + 255) / 256; // 128
  const int wsBlocks = (256 * 128 + 128 * 64 + 1023) / 1024; // 40

  hist_wsplit_kernel<<<NB + wsBlocks, 1024, 0, stream>>>(src, dst, part, W1, W2, WhT1, WlT1,
                                                         WhT2, E, epb);
  norm_partial<<<dim3(N4 / 256, RSEG, 2), 256, 0, stream>>>(part, psum, N4);
  norm_final<<<N4 / 256, 256, 0, stream>>>(psum, norm_src, norm_dst, in_deg, block_sums, N4);
  scan_write_goffs<<<nBlocks, 256, 0, stream>>>(in_deg, block_sums, part_dst, row_ptr, gpre, N);
  scatter_kernel<<<NB, 1024, 0, stream>>>(src, dst, ew, norm_src, row_ptr, gpre, csr, N, E, epb);

  // Layer 1 transform: 256 -> 128 (output bf16)
  gemm_mfma<256, 128><<<N / 64, 256, 0, stream>>>(b_z, WhT1, WlT1, HT1, N);
  // Fused: layer-1 aggregate (tanh) + layer-2 transform (128 -> 64)
  agg1_gemm2<<<N / 64, 256, 0, stream>>>(HT1, row_ptr, csr, norm_dst, b1, WhT2, HT2, N);
  // Layer 2 aggregate (tanh) fused with layer-3 transform (64 -> 1)
  aggregate2_fuse3<<<(N + 15) / 16, 256, 0, stream>>>(HT2, row_ptr, csr, norm_dst, b2, W3, HT3, N);
  // Layer 3 aggregate: 1 col, no tanh
  aggregate3_kernel<<<nBlocks, 256, 0, stream>>>(HT3, row_ptr, csr, norm_dst, b3,
                                                 (float*)d_out, N);
}

// Round 19
// 105.783 us; speedup vs baseline: 1.1605x; 1.1605x over previous
//
#include <hip/hip_runtime.h>

// ---------------------------------------------------------------------------
// GCN 3-layer forward on a static graph.
// R2-R6: tiled SGEMM, parallel scan, int2 CSR, LDS histograms/rank-scatter.
// R7-R9: f32 SGEMM structurally capped ~45us (LDS pipe vs 4 SIMDs).
// R10: bf16 split-precision MFMA GEMM: 168->141.5us.
// R11: bf16 HT gather operand: ->124us (absmax 3e-5 -> 6.1e-5).
// R12: preprocessing occupancy (NB=256, u8 gpre, 2-stage norm): ->111.5us.
// R13: gemm reg-prefetch; ACT1 bf16; norm folded into csr_w: ->107.7us.
// R14: calibrated precision cuts (gemm1 2 MFMA, gemm2 1 MFMA, fast tanh):
//     ->105.4us, absmax pinned 6.1e-5.  *** BEST ***
// R15/R16: cooperative mega-fusion DEAD (grid.sync ~35us each across 8
//     non-coherent XCD L2s; 4 syncs = 140us alone).
// R17: norm_reduce fusion NEGATIVE (+2.7us): fused kernel serializes 64
//     partials/thread; launch-gap saving < kernel slowdown.
// R18: agg1+gemm2 fusion NEGATIVE (+17us): 35KB LDS tile cut occupancy to
//     17% and destroyed the gather's TLP latency hiding. Lesson: never
//     attach occupancy-limiting resources to a latency-bound gather.
// R19: revert to R14 exactly. Structural plateau: gather kernels at L2/L3
//     latency floor with max occupancy, MFMA transforms ~9us total,
//     preprocessing ~26us, ~25-30us launch gaps that resist fusion.
// ---------------------------------------------------------------------------

#define NB 256     // edge groups == hist/scatter blocks
#define NW4 8192   // N/4 packed words (N = 32768)
#define RSEG 8     // r-segments for the 2-stage partials reduction

typedef unsigned int uint32;
typedef unsigned char uchar_t;
typedef unsigned short ushort_t;
typedef __attribute__((ext_vector_type(8))) short bf16x8;
typedef __attribute__((ext_vector_type(4))) float f32x4;

__device__ inline ushort_t f2bf(float f) {
  uint32 u = __float_as_uint(f);
  u += 0x7fffu + ((u >> 16) & 1u);
  return (ushort_t)(u >> 16);
}
__device__ inline float bf2f(ushort_t h) { return __uint_as_float(((uint32)h) << 16); }

// tanh = (e^{2x}-1)/(e^{2x}+1); clamp keeps t finite, rcp approx ~1ulp.
__device__ inline float fast_tanh(float x) {
  float xc = fminf(fmaxf(x, -30.f), 30.f);
  float t = __expf(2.0f * xc);
  return (t - 1.0f) * __builtin_amdgcn_rcpf(t + 1.0f);
}

// --- hist (blocks < NB) + W pre-split (blocks >= NB) ------------------------
__global__ __launch_bounds__(1024) void hist_wsplit_kernel(
    const int* __restrict__ src, const int* __restrict__ dst, uint32* __restrict__ part,
    const float* __restrict__ W1, const float* __restrict__ W2,
    ushort_t* __restrict__ WhT1, ushort_t* __restrict__ WlT1,
    ushort_t* __restrict__ WhT2, int e, int epb) {
  const int t = threadIdx.x;
  if (blockIdx.x >= NB) {
    int i = (blockIdx.x - NB) * 1024 + t;
    if (i < 256 * 128) {
      int k = i / 128, c = i % 128;
      float f = W1[i];
      ushort_t h = f2bf(f);
      WhT1[(size_t)c * 256 + k] = h;
      WlT1[(size_t)c * 256 + k] = f2bf(f - bf2f(h));
    } else if (i < 256 * 128 + 128 * 64) {
      int j = i - 256 * 128;
      int k = j / 64, c = j % 64;
      WhT2[(size_t)c * 128 + k] = f2bf(W2[j]);
    }
    return;
  }
  __shared__ uint32 hs[NW4];
  __shared__ uint32 hd[NW4];
  for (int w = t; w < NW4; w += 1024) {
    hs[w] = 0;
    hd[w] = 0;
  }
  __syncthreads();
  const int base = blockIdx.x * epb;
  for (int k = t; k < epb; k += 1024) {
    int i = base + k;
    if (i < e) {
      int s = src[i], d = dst[i];
      atomicAdd(&hs[s >> 2], 1u << ((s & 3) * 8));
      atomicAdd(&hd[d >> 2], 1u << ((d & 3) * 8));
    }
  }
  __syncthreads();
  uint32* ps = part + (size_t)blockIdx.x * NW4;
  uint32* pd = part + (size_t)(NB + blockIdx.x) * NW4;
  for (int w = t; w < NW4; w += 1024) {
    ps[w] = hs[w];
    pd[w] = hd[w];
  }
}

// --- stage A: sum NB/RSEG r-values per word per segment ---------------------
__global__ __launch_bounds__(256) void norm_partial(const uint32* __restrict__ part,
                                                    uint32* __restrict__ psum, int n4) {
  const int w = blockIdx.x * 256 + threadIdx.x;
  const int seg = blockIdx.y;
  const int a = blockIdx.z;
  const uint32* p = part + (size_t)a * NB * n4 + (size_t)seg * (NB / RSEG) * n4 + w;
  uint32 s = 0;
#pragma unroll
  for (int r = 0; r < NB / RSEG; ++r) s += p[(size_t)r * n4];
  psum[(size_t)a * RSEG * n4 + (size_t)seg * n4 + w] = s;
}

// --- stage B: fold segments -> norms/in_deg + chunk sums --------------------
__global__ __launch_bounds__(256) void norm_final(const uint32* __restrict__ psum,
                                                  float* __restrict__ norm_src,
                                                  float* __restrict__ norm_dst,
                                                  int* __restrict__ in_deg,
                                                  int* __restrict__ block_sums, int n4) {
  const int w = blockIdx.x * 256 + threadIdx.x;
  if (w >= n4) return;
  uint32 ss = 0, sd = 0;
#pragma unroll
  for (int seg = 0; seg < RSEG; ++seg) {
    ss += psum[(size_t)seg * n4 + w];
    sd += psum[(size_t)(RSEG + seg) * n4 + w];
  }
  int idsum = 0;
#pragma unroll
  for (int j = 0; j < 4; ++j) {
    int v = w * 4 + j;
    int od = (ss >> (j * 8)) & 0xff;
    int id = (sd >> (j * 8)) & 0xff;
    norm_src[v] = 1.0f / sqrtf((float)max(od, 1));
    norm_dst[v] = 1.0f / sqrtf((float)max(id, 1));
    in_deg[v] = id;
    idsum += id;
  }
#pragma unroll
  for (int off = 32; off > 0; off >>= 1) idsum += __shfl_down(idsum, off, 64);
  if ((threadIdx.x & 63) == 0) block_sums[w >> 6] = idsum;
}

// --- chunk scan (block offset inlined) -> row_ptr + u8 group offsets --------
__global__ __launch_bounds__(256) void scan_write_goffs(const int* __restrict__ in_deg,
                                                        const int* __restrict__ block_sums,
                                                        const uint32* __restrict__ part_dst,
                                                        int* __restrict__ row_ptr,
                                                        uchar_t* __restrict__ gpre, int n) {
  __shared__ int sh[256];
  __shared__ int s_boff;
  const int t = threadIdx.x;
  const int gid = blockIdx.x * 256 + t;
  {
    int v = (t < blockIdx.x && t < 128) ? block_sums[t] : 0;
#pragma unroll
    for (int off = 32; off > 0; off >>= 1) v += __shfl_down(v, off, 64);
    if ((t & 63) == 0) sh[t >> 6] = v;
    __syncthreads();
    if (t == 0) s_boff = sh[0] + sh[1];
    __syncthreads();
  }
  int d = (gid < n) ? in_deg[gid] : 0;
  sh[t] = d;
  __syncthreads();
  for (int off = 1; off < 256; off <<= 1) {
    int v = sh[t];
    int add = (t >= off) ? sh[t - off] : 0;
    __syncthreads();
    sh[t] = v + add;
    __syncthreads();
  }
  if (gid >= n) return;
  int excl = s_boff + sh[t] - d;
  row_ptr[gid] = excl;
  if (gid == n - 1) row_ptr[n] = excl + d;
  const int w = gid >> 2;
  const int shft = (gid & 3) * 8;
  const int n4 = n >> 2;
  int cum = 0;
#pragma unroll 8
  for (int r = 0; r < NB; ++r) {
    gpre[(size_t)r * n + gid] = (uchar_t)cum;
    cum += (part_dst[(size_t)r * n4 + w] >> shft) & 0xff;
  }
}

// --- scatter: LDS rank + row_ptr + gpre; csr weight = ew * norm_src[src] ----
__global__ __launch_bounds__(1024) void scatter_kernel(const int* __restrict__ src,
                                                       const int* __restrict__ dst,
                                                       const float* __restrict__ ew,
                                                       const float* __restrict__ norm_src,
                                                       const int* __restrict__ row_ptr,
                                                       const uchar_t* __restrict__ gpre,
                                                       int2* __restrict__ csr,
                                                       int n, int e, int epb) {
  __shared__ uint32 rk[NW4];
  const int t = threadIdx.x;
  for (int w = t; w < NW4; w += 1024) rk[w] = 0;
  __syncthreads();
  const int base = blockIdx.x * epb;
  const uchar_t* gp = gpre + (size_t)blockIdx.x * n;
  for (int k = t; k < epb; k += 1024) {
    int i = base + k;
    if (i < e) {
      int s = src[i];
      int d = dst[i];
      uint32 sh = (d & 3) * 8;
      uint32 old = atomicAdd(&rk[d >> 2], 1u << sh);
      int rank = (old >> sh) & 0xff;
      int pos = row_ptr[d] + (int)gp[d] + rank;
      csr[pos] = make_int2(s, __float_as_int(ew[i] * norm_src[s]));
    }
  }
}

// ---------------------------------------------------------------------------
// MFMA GEMM, f32 input rounded to bf16-high: ht = bf16(x @ W), 2 MFMAs
// (ah*bh + ah*bl). Register-prefetch of next chunk hides cold-load latency.
// ---------------------------------------------------------------------------
template <int K, int OUT>
__global__ __launch_bounds__(256) void gemm_mfma(const float* __restrict__ x,
                                                 const ushort_t* __restrict__ WhT,
                                                 const ushort_t* __restrict__ WlT,
                                                 ushort_t* __restrict__ ht, int n) {
  constexpr int BK = 64, KP = BK + 8;
  constexpr int NCT = OUT / 32;
  constexpr int NWLD = OUT * 16 / 256;
  __shared__ ushort_t Xh[64][KP];
  __shared__ ushort_t Wh[OUT][KP], Wl[OUT][KP];

  const int tid = threadIdx.x;
  const int wv = tid >> 6;
  const int lane = tid & 63;
  const int wr = wv >> 1;
  const int wc = wv & 1;
  const int row0 = blockIdx.x * 64;
  const int fr = lane & 15;
  const int fg = lane >> 4;

  f32x4 acc[2][NCT];
#pragma unroll
  for (int i = 0; i < 2; ++i)
#pragma unroll
    for (int j = 0; j < NCT; ++j) acc[i][j] = (f32x4){0.f, 0.f, 0.f, 0.f};

  float4 xr[4];
  ushort4 wrh[NWLD], wrl[NWLD];

#define LOADX(kg)                                                                       \
  {                                                                                     \
    _Pragma("unroll") for (int p_ = 0; p_ < 4; ++p_) {                                  \
      int idx_ = p_ * 256 + tid;                                                        \
      xr[p_] = *reinterpret_cast<const float4*>(                                        \
          x + (size_t)(row0 + (idx_ >> 4)) * K + (kg) + (idx_ & 15) * 4);               \
    }                                                                                   \
  }
#define LOADW(kg)                                                                       \
  {                                                                                     \
    _Pragma("unroll") for (int p_ = 0; p_ < NWLD; ++p_) {                               \
      int idx_ = p_ * 256 + tid;                                                        \
      int c_ = idx_ >> 4, k4_ = idx_ & 15;                                              \
      wrh[p_] = *reinterpret_cast<const ushort4*>(WhT + (size_t)c_ * K + (kg) + k4_ * 4);\
      wrl[p_] = *reinterpret_cast<const ushort4*>(WlT + (size_t)c_ * K + (kg) + k4_ * 4);\
    }                                                                                   \
  }

  LOADX(0);
  LOADW(0);

#pragma unroll 1
  for (int k0 = 0; k0 < K; k0 += BK) {
    __syncthreads();
#pragma unroll
    for (int p = 0; p < 4; ++p) {
      int idx = p * 256 + tid;
      int r = idx >> 4, c4 = idx & 15;
      float4 v = xr[p];
      ushort4 h;
      h.x = f2bf(v.x);
      h.y = f2bf(v.y);
      h.z = f2bf(v.z);
      h.w = f2bf(v.w);
      *reinterpret_cast<ushort4*>(&Xh[r][c4 * 4]) = h;
    }
#pragma unroll
    for (int p = 0; p < NWLD; ++p) {
      int idx = p * 256 + tid;
      int c = idx >> 4, k4 = idx & 15;
      *reinterpret_cast<ushort4*>(&Wh[c][k4 * 4]) = wrh[p];
      *reinterpret_cast<ushort4*>(&Wl[c][k4 * 4]) = wrl[p];
    }
    if (k0 + BK < K) {
      LOADX(k0 + BK);
      LOADW(k0 + BK);
    }
    __syncthreads();

#pragma unroll
    for (int s = 0; s < 2; ++s) {
      const int kk = s * 32 + fg * 8;
      bf16x8 ah[2];
#pragma unroll
      for (int i = 0; i < 2; ++i)
        ah[i] = *reinterpret_cast<const bf16x8*>(&Xh[wr * 32 + i * 16 + fr][kk]);
#pragma unroll
      for (int j = 0; j < NCT; ++j) {
        int c = wc * (OUT / 2) + j * 16 + fr;
        bf16x8 bh = *reinterpret_cast<const bf16x8*>(&Wh[c][kk]);
        bf16x8 bl = *reinterpret_cast<const bf16x8*>(&Wl[c][kk]);
#pragma unroll
        for (int i = 0; i < 2; ++i) {
          acc[i][j] = __builtin_amdgcn_mfma_f32_16x16x32_bf16(ah[i], bh, acc[i][j], 0, 0, 0);
          acc[i][j] = __builtin_amdgcn_mfma_f32_16x16x32_bf16(ah[i], bl, acc[i][j], 0, 0, 0);
        }
      }
    }
  }
#undef LOADX
#undef LOADW

#pragma unroll
  for (int i = 0; i < 2; ++i) {
#pragma unroll
    for (int q = 0; q < 4; ++q) {
      int row = row0 + wr * 32 + i * 16 + fg * 4 + q;
#pragma unroll
      for (int j = 0; j < NCT; ++j) {
        int col = wc * (OUT / 2) + j * 16 + fr;
        ht[(size_t)row * OUT + col] = f2bf(acc[i][j][q]);
      }
    }
  }
}

// ---------------------------------------------------------------------------
// bf16-input MFMA GEMM, W bf16-high only: 1 MFMA per fragment.
// ---------------------------------------------------------------------------
template <int K, int OUT>
__global__ __launch_bounds__(256) void gemm_mfma_bf16in(const ushort_t* __restrict__ x,
                                                        const ushort_t* __restrict__ WhT,
                                                        ushort_t* __restrict__ ht, int n) {
  constexpr int BK = 64, KP = BK + 8;
  constexpr int NCT = OUT / 32;
  constexpr int NWLD = OUT * 16 / 256;
  __shared__ ushort_t Xh[64][KP];
  __shared__ ushort_t Wh[OUT][KP];

  const int tid = threadIdx.x;
  const int wv = tid >> 6;
  const int lane = tid & 63;
  const int wr = wv >> 1;
  const int wc = wv & 1;
  const int row0 = blockIdx.x * 64;
  const int fr = lane & 15;
  const int fg = lane >> 4;

  f32x4 acc[2][NCT];
#pragma unroll
  for (int i = 0; i < 2; ++i)
#pragma unroll
    for (int j = 0; j < NCT; ++j) acc[i][j] = (f32x4){0.f, 0.f, 0.f, 0.f};

  ushort4 xr[4];
  ushort4 wrh[NWLD];

#define LOADX(kg)                                                                       \
  {                                                                                     \
    _Pragma("unroll") for (int p_ = 0; p_ < 4; ++p_) {                                  \
      int idx_ = p_ * 256 + tid;                                                        \
      xr[p_] = *reinterpret_cast<const ushort4*>(                                       \
          x + (size_t)(row0 + (idx_ >> 4)) * K + (kg) + (idx_ & 15) * 4);               \
    }                                                                                   \
  }
#define LOADW(kg)                                                                       \
  {                                                                                     \
    _Pragma("unroll") for (int p_ = 0; p_ < NWLD; ++p_) {                               \
      int idx_ = p_ * 256 + tid;                                                        \
      int c_ = idx_ >> 4, k4_ = idx_ & 15;                                              \
      wrh[p_] = *reinterpret_cast<const ushort4*>(WhT + (size_t)c_ * K + (kg) + k4_ * 4);\
    }                                                                                   \
  }

  LOADX(0);
  LOADW(0);

#pragma unroll 1
  for (int k0 = 0; k0 < K; k0 += BK) {
    __syncthreads();
#pragma unroll
    for (int p = 0; p < 4; ++p) {
      int idx = p * 256 + tid;
      *reinterpret_cast<ushort4*>(&Xh[idx >> 4][(idx & 15) * 4]) = xr[p];
    }
#pragma unroll
    for (int p = 0; p < NWLD; ++p) {
      int idx = p * 256 + tid;
      *reinterpret_cast<ushort4*>(&Wh[idx >> 4][(idx & 15) * 4]) = wrh[p];
    }
    if (k0 + BK < K) {
      LOADX(k0 + BK);
      LOADW(k0 + BK);
    }
    __syncthreads();

#pragma unroll
    for (int s = 0; s < 2; ++s) {
      const int kk = s * 32 + fg * 8;
      bf16x8 ah[2];
#pragma unroll
      for (int i = 0; i < 2; ++i)
        ah[i] = *reinterpret_cast<const bf16x8*>(&Xh[wr * 32 + i * 16 + fr][kk]);
#pragma unroll
      for (int j = 0; j < NCT; ++j) {
        int c = wc * (OUT / 2) + j * 16 + fr;
        bf16x8 bh = *reinterpret_cast<const bf16x8*>(&Wh[c][kk]);
#pragma unroll
        for (int i = 0; i < 2; ++i)
          acc[i][j] = __builtin_amdgcn_mfma_f32_16x16x32_bf16(ah[i], bh, acc[i][j], 0, 0, 0);
      }
    }
  }
#undef LOADX
#undef LOADW

#pragma unroll
  for (int i = 0; i < 2; ++i) {
#pragma unroll
    for (int q = 0; q < 4; ++q) {
      int row = row0 + wr * 32 + i * 16 + fg * 4 + q;
#pragma unroll
      for (int j = 0; j < NCT; ++j) {
        int col = wc * (OUT / 2) + j * 16 + fr;
        ht[(size_t)row * OUT + col] = f2bf(acc[i][j][q]);
      }
    }
  }
}

// bf16 gather: 4 bf16 (8B) per lane-group slot
#define GATHB(e, acc)                                                               \
  {                                                                                 \
    float w_ = __int_as_float(e.y);                                                 \
    ushort4 h_ = *reinterpret_cast<const ushort4*>(ht + (size_t)e.x * OUT + cg * 4);\
    acc.x += w_ * bf2f(h_.x);                                                       \
    acc.y += w_ * bf2f(h_.y);                                                       \
    acc.z += w_ * bf2f(h_.z);                                                       \
    acc.w += w_ * bf2f(h_.w);                                                       \
  }

// out[v] = tanh(nd*sum + b), written bf16
template <int OUT>
__global__ void aggregate_kernel(const ushort_t* __restrict__ ht, const int* __restrict__ row_ptr,
                                 const int2* __restrict__ csr, const float* __restrict__ norm_dst,
                                 const float* __restrict__ bias, ushort_t* __restrict__ out,
                                 int n) {
  constexpr int LPN = OUT / 4;
  constexpr int NPB = 256 / LPN;
  const int tid = threadIdx.x;
  const int cg = tid % LPN;
  const int v = blockIdx.x * NPB + tid / LPN;
  if (v >= n) return;

  const int s0 = row_ptr[v];
  const int s1 = row_ptr[v + 1];
  float4 a0 = {0, 0, 0, 0}, a1 = {0, 0, 0, 0}, a2 = {0, 0, 0, 0}, a3 = {0, 0, 0, 0};
  int i = s0;
  for (; i + 4 <= s1; i += 4) {
    int2 e0 = csr[i], e1 = csr[i + 1], e2 = csr[i + 2], e3 = csr[i + 3];
    GATHB(e0, a0);
    GATHB(e1, a1);
    GATHB(e2, a2);
    GATHB(e3, a3);
  }
  for (; i < s1; ++i) {
    int2 e = csr[i];
    GATHB(e, a0);
  }
  float nd = norm_dst[v];
  float4 b4 = *reinterpret_cast<const float4*>(bias + cg * 4);
  ushort4 r;
  r.x = f2bf(fast_tanh((a0.x + a1.x + a2.x + a3.x) * nd + b4.x));
  r.y = f2bf(fast_tanh((a0.y + a1.y + a2.y + a3.y) * nd + b4.y));
  r.z = f2bf(fast_tanh((a0.z + a1.z + a2.z + a3.z) * nd + b4.z));
  r.w = f2bf(fast_tanh((a0.w + a1.w + a2.w + a3.w) * nd + b4.w));
  *reinterpret_cast<ushort4*>(out + (size_t)v * OUT + cg * 4) = r;
}

// Layer-2 aggregate fused with layer-3 transform (norm folded into csr_w).
__global__ void aggregate2_fuse3(const ushort_t* __restrict__ ht, const int* __restrict__ row_ptr,
                                 const int2* __restrict__ csr, const float* __restrict__ norm_dst,
                                 const float* __restrict__ bias, const float* __restrict__ W3,
                                 float* __restrict__ ht3, int n) {
  constexpr int OUT = 64;
  constexpr int LPN = OUT / 4; // 16
  constexpr int NPB = 256 / LPN;
  const int tid = threadIdx.x;
  const int cg = tid % LPN;
  const int v = blockIdx.x * NPB + tid / LPN;
  if (v >= n) return;

  const int s0 = row_ptr[v];
  const int s1 = row_ptr[v + 1];
  float4 a0 = {0, 0, 0, 0}, a1 = {0, 0, 0, 0}, a2 = {0, 0, 0, 0}, a3 = {0, 0, 0, 0};
  int i = s0;
  for (; i + 4 <= s1; i += 4) {
    int2 e0 = csr[i], e1 = csr[i + 1], e2 = csr[i + 2], e3 = csr[i + 3];
    GATHB(e0, a0);
    GATHB(e1, a1);
    GATHB(e2, a2);
    GATHB(e3, a3);
  }
  for (; i < s1; ++i) {
    int2 e = csr[i];
    GATHB(e, a0);
  }
  float nd = norm_dst[v];
  float4 b4 = *reinterpret_cast<const float4*>(bias + cg * 4);
  float ox = fast_tanh((a0.x + a1.x + a2.x + a3.x) * nd + b4.x);
  float oy = fast_tanh((a0.y + a1.y + a2.y + a3.y) * nd + b4.y);
  float oz = fast_tanh((a0.z + a1.z + a2.z + a3.z) * nd + b4.z);
  float ow = fast_tanh((a0.w + a1.w + a2.w + a3.w) * nd + b4.w);
  float4 w3 = *reinterpret_cast<const float4*>(W3 + cg * 4);
  float p = ox * w3.x + oy * w3.y + oz * w3.z + ow * w3.w;
#pragma unroll
  for (int m = 1; m < 16; m <<= 1) p += __shfl_xor(p, m, 64);
  if (cg == 0) ht3[v] = p;
}

__global__ void aggregate3_kernel(const float* __restrict__ ht3, const int* __restrict__ row_ptr,
                                  const int2* __restrict__ csr, const float* __restrict__ norm_dst,
                                  const float* __restrict__ b3, float* __restrict__ out, int n) {
  int v = blockIdx.x * blockDim.x + threadIdx.x;
  if (v >= n) return;
  const int s0 = row_ptr[v];
  const int s1 = row_ptr[v + 1];
  float p0 = 0.f, p1 = 0.f, p2 = 0.f, p3 = 0.f;
  int i = s0;
  for (; i + 4 <= s1; i += 4) {
    int2 e0 = csr[i], e1 = csr[i + 1], e2 = csr[i + 2], e3 = csr[i + 3];
    p0 += __int_as_float(e0.y) * ht3[e0.x];
    p1 += __int_as_float(e1.y) * ht3[e1.x];
    p2 += __int_as_float(e2.y) * ht3[e2.x];
    p3 += __int_as_float(e3.y) * ht3[e3.x];
  }
  for (; i < s1; ++i) {
    int2 e = csr[i];
    p0 += __int_as_float(e.y) * ht3[e.x];
  }
  out[v] = (p0 + p1 + p2 + p3) * norm_dst[v] + b3[0];
}

extern "C" void kernel_launch(void* const* d_in, const int* in_sizes, int n_in,
                              void* d_out, int out_size, void* d_ws, size_t ws_size,
                              hipStream_t stream) {
  const float* b_z = (const float*)d_in[0];
  const int* src = (const int*)d_in[1];
  const int* dst = (const int*)d_in[2];
  const float* ew = (const float*)d_in[3];
  const float* W1 = (const float*)d_in[4];
  const float* b1 = (const float*)d_in[5];
  const float* W2 = (const float*)d_in[6];
  const float* b2 = (const float*)d_in[7];
  const float* W3 = (const float*)d_in[8];
  const float* b3 = (const float*)d_in[9];

  const int N = in_sizes[0] / 256; // 32768
  const int E = in_sizes[1];       // 524288
  const int N4 = N / 4;            // 8192
  const int epb = (E + NB - 1) / NB; // 2048

  char* ws = (char*)d_ws;
  size_t off = 0;
  auto alloc = [&](size_t bytes) -> void* {
    void* p = ws + off;
    off += (bytes + 255) & ~(size_t)255;
    return p;
  };

  uint32* part = (uint32*)alloc((size_t)2 * NB * N4 * 4);   // 16 MB
  uint32* psum = (uint32*)alloc((size_t)2 * RSEG * N4 * 4); // 512 KB
  uchar_t* gpre = (uchar_t*)alloc((size_t)NB * N);          // 8 MB
  float* norm_src = (float*)alloc((size_t)N * 4);
  float* norm_dst = (float*)alloc((size_t)N * 4);
  int* in_deg = (int*)alloc((size_t)N * 4);
  int* row_ptr = (int*)alloc((size_t)(N + 1) * 4);
  int* block_sums = (int*)alloc(256 * 4);
  int2* csr = (int2*)alloc((size_t)E * 8);
  ushort_t* HT = (ushort_t*)alloc((size_t)N * 128 * 2);   // bf16 ht1 / ht2 (reused)
  ushort_t* ACT1 = (ushort_t*)alloc((size_t)N * 128 * 2); // bf16 layer1 activation
  float* HT3 = (float*)alloc((size_t)N * 4);
  ushort_t* WhT1 = (ushort_t*)alloc((size_t)256 * 128 * 2);
  ushort_t* WlT1 = (ushort_t*)alloc((size_t)256 * 128 * 2);
  ushort_t* WhT2 = (ushort_t*)alloc((size_t)128 * 64 * 2);

  const uint32* part_dst = part + (size_t)NB * N4;
  const int nBlocks = (N + 255) / 256; // 128
  const int wsBlocks = (256 * 128 + 128 * 64 + 1023) / 1024; // 40

  hist_wsplit_kernel<<<NB + wsBlocks, 1024, 0, stream>>>(src, dst, part, W1, W2, WhT1, WlT1,
                                                         WhT2, E, epb);
  norm_partial<<<dim3(N4 / 256, RSEG, 2), 256, 0, stream>>>(part, psum, N4);
  norm_final<<<N4 / 256, 256, 0, stream>>>(psum, norm_src, norm_dst, in_deg, block_sums, N4);
  scan_write_goffs<<<nBlocks, 256, 0, stream>>>(in_deg, block_sums, part_dst, row_ptr, gpre, N);
  scatter_kernel<<<NB, 1024, 0, stream>>>(src, dst, ew, norm_src, row_ptr, gpre, csr, N, E, epb);

  // Layer 1: 256 -> 128, tanh (output bf16)
  gemm_mfma<256, 128><<<N / 64, 256, 0, stream>>>(b_z, WhT1, WlT1, HT, N);
  aggregate_kernel<128><<<(N + 7) / 8, 256, 0, stream>>>(HT, row_ptr, csr, norm_dst, b1, ACT1, N);
  // Layer 2: 128 -> 64 (tanh) fused with layer-3 transform (64 -> 1)
  gemm_mfma_bf16in<128, 64><<<N / 64, 256, 0, stream>>>(ACT1, WhT2, HT, N);
  aggregate2_fuse3<<<(N + 15) / 16, 256, 0, stream>>>(HT, row_ptr, csr, norm_dst, b2, W3, HT3, N);
  // Layer 3 aggregate: 1 col, no tanh
  aggregate3_kernel<<<nBlocks, 256, 0, stream>>>(HT3, row_ptr, csr, norm_dst, b3,
                                                 (float*)d_out, N);
}